// Round 1
// baseline (898.174 us; speedup 1.0000x reference)
//
#include <hip/hip_runtime.h>
#include <hip/hip_bf16.h>
#include <stdint.h>

// NNUE bucket model, fp16-MFMA plan:
//   K1: convert x (B,1540) fp32 -> x16 (2B,800) fp16 (pad 770->800), fused pc/bucket
//   K2: convert ft_w -> (512,800) fp16 padded, h1_w -> (256,1024) fp16
//   K3: GEMM1 (2B,800)x(512,800)^T -> crelu(+ft_b) -> C1 (2B,512) fp16   [m97-style]
//   K4: GEMM2 (B,1024)x(256,1024)^T -> crelu(+h1_b) -> H (B,256) fp32
//       (A row = concat of C1[m] and C1[B+m], resolved per K-tile)
//   K5: tail: per sample, bucket-selected h2 (32x32) + h3 dot, 32 lanes/sample

#define INF 770
#define KP  800
#define FT  512
#define K2  1024
#define N2  256

typedef _Float16 half8 __attribute__((ext_vector_type(8)));
typedef float floatx4 __attribute__((ext_vector_type(4)));

__device__ __forceinline__ float crelu_f(float v) {
    return v < 0.f ? 0.f : (v > 1.f ? 1.f : v);
}

__device__ __forceinline__ void gl_lds16(const _Float16* g, _Float16* l) {
    __builtin_amdgcn_global_load_lds(
        (__attribute__((address_space(1))) void*)(uintptr_t)(const void*)g,
        (__attribute__((address_space(3))) void*)l,
        16, 0, 0);
}

// ---------------- K1: convert x + bucket ----------------
__global__ __launch_bounds__(256) void convert_x_kernel(
    const float* __restrict__ x, _Float16* __restrict__ x16,
    int* __restrict__ bucket, int B)
{
    __shared__ float red[4];
    int b = blockIdx.x;
    int tid = threadIdx.x, lane = tid & 63, w = tid >> 6;
    const float* src = x + (size_t)b * (2 * INF);
    _Float16* d0 = x16 + (size_t)b * KP;
    _Float16* d1 = x16 + ((size_t)B + b) * KP;
    float s = 0.f;
    for (int i = tid; i < KP; i += 256) {
        float v0 = 0.f, v1 = 0.f;
        if (i < INF) { v0 = src[i]; v1 = src[INF + i]; }
        d0[i] = (_Float16)v0;
        d1[i] = (_Float16)v1;
        if (i < 768) s += v0;
    }
    #pragma unroll
    for (int off = 32; off; off >>= 1) s += __shfl_down(s, off, 64);
    if (lane == 0) red[w] = s;
    __syncthreads();
    if (tid == 0) {
        float pc = red[0] + red[1] + red[2] + red[3];
        int bk = (int)(pc * (8.0f / 33.0f));
        bucket[b] = bk < 0 ? 0 : (bk > 7 ? 7 : bk);
    }
}

// ---------------- K2: convert weights ----------------
__global__ __launch_bounds__(256) void convert_w_kernel(
    const float* __restrict__ ftw, const float* __restrict__ h1w,
    _Float16* __restrict__ ftw16, _Float16* __restrict__ h1w16)
{
    int idx = blockIdx.x * 256 + threadIdx.x;
    const int FTW = FT * KP;            // 409600
    if (idx < FTW) {
        int r = idx / KP, c = idx - r * KP;
        ftw16[idx] = (_Float16)(c < INF ? ftw[r * INF + c] : 0.f);
    } else {
        int j = idx - FTW;
        if (j < N2 * K2) h1w16[j] = (_Float16)h1w[j];
    }
}

// ---------------- K3: GEMM1 (FT layer) ----------------
// C[gm][gn] = crelu( sum_k A[gm][k]*Bt[gn][k] + bias[gn] ), fp16 out
__global__ __launch_bounds__(256) void gemm_ft_kernel(
    const _Float16* __restrict__ A,   // (2B, 800)
    const _Float16* __restrict__ Bt,  // (512, 800)
    const float* __restrict__ bias,   // (512)
    _Float16* __restrict__ C)         // (2B, 512)
{
    __shared__ _Float16 lsA[128 * 32];
    __shared__ _Float16 lsB[128 * 32];
    int bid = blockIdx.x;
    int mt = bid >> 2, nt = bid & 3;
    int m0 = mt * 128, n0 = nt * 128;
    int tid = threadIdx.x, lane = tid & 63, w = tid >> 6;
    int rm = (w & 1) * 64, rn = (w >> 1) * 64;
    int colL = lane & 15, rowQ = lane >> 4;

    floatx4 acc[4][4] = {};

    for (int kt = 0; kt < KP / 32; ++kt) {
        int ks = kt * 32;
        #pragma unroll
        for (int p = 0; p < 2; ++p) {
            int qb = p * 256 + w * 64;
            int q = qb + lane;
            int r = q >> 2, c8 = q & 3;
            gl_lds16(A + (size_t)(m0 + r) * KP + ks + c8 * 8, lsA + qb * 8);
            gl_lds16(Bt + (size_t)(n0 + r) * KP + ks + c8 * 8, lsB + qb * 8);
        }
        asm volatile("s_waitcnt vmcnt(0)" ::: "memory");
        __syncthreads();

        half8 af[4], bf[4];
        #pragma unroll
        for (int i = 0; i < 4; ++i)
            af[i] = *(const half8*)(lsA + (rm + i * 16 + colL) * 32 + rowQ * 8);
        #pragma unroll
        for (int j = 0; j < 4; ++j)
            bf[j] = *(const half8*)(lsB + (rn + j * 16 + colL) * 32 + rowQ * 8);
        #pragma unroll
        for (int i = 0; i < 4; ++i)
            #pragma unroll
            for (int j = 0; j < 4; ++j)
                acc[i][j] = __builtin_amdgcn_mfma_f32_16x16x32_f16(af[i], bf[j], acc[i][j], 0, 0, 0);
        __syncthreads();
    }

    #pragma unroll
    for (int j = 0; j < 4; ++j) {
        int gn = n0 + rn + j * 16 + colL;
        float bv = bias[gn];
        #pragma unroll
        for (int i = 0; i < 4; ++i) {
            #pragma unroll
            for (int r = 0; r < 4; ++r) {
                int gm = m0 + rm + i * 16 + rowQ * 4 + r;
                float v = crelu_f(acc[i][j][r] + bv);
                C[(size_t)gm * FT + gn] = (_Float16)v;
            }
        }
    }
}

// ---------------- K4: GEMM2 (h1 layer, all buckets) ----------------
__global__ __launch_bounds__(256) void gemm_h1_kernel(
    const _Float16* __restrict__ C1,  // (2B, 512)
    const _Float16* __restrict__ Bt,  // (256, 1024)
    const float* __restrict__ bias,   // (256)
    float* __restrict__ H,            // (B, 256)
    int B)
{
    __shared__ _Float16 lsA[128 * 32];
    __shared__ _Float16 lsB[128 * 32];
    int bid = blockIdx.x;
    int mt = bid >> 1, nt = bid & 1;
    int m0 = mt * 128, n0 = nt * 128;
    int tid = threadIdx.x, lane = tid & 63, w = tid >> 6;
    int rm = (w & 1) * 64, rn = (w >> 1) * 64;
    int colL = lane & 15, rowQ = lane >> 4;

    floatx4 acc[4][4] = {};

    for (int kt = 0; kt < K2 / 32; ++kt) {
        int ks = kt * 32;
        // combined[m][k] = k<512 ? C1[m][k] : C1[B+m][k-512]
        const _Float16* Abase = (ks < FT) ? (C1 + ks)
                                          : (C1 + (size_t)B * FT + (ks - FT));
        #pragma unroll
        for (int p = 0; p < 2; ++p) {
            int qb = p * 256 + w * 64;
            int q = qb + lane;
            int r = q >> 2, c8 = q & 3;
            gl_lds16(Abase + (size_t)(m0 + r) * FT + c8 * 8, lsA + qb * 8);
            gl_lds16(Bt + (size_t)(n0 + r) * K2 + ks + c8 * 8, lsB + qb * 8);
        }
        asm volatile("s_waitcnt vmcnt(0)" ::: "memory");
        __syncthreads();

        half8 af[4], bf[4];
        #pragma unroll
        for (int i = 0; i < 4; ++i)
            af[i] = *(const half8*)(lsA + (rm + i * 16 + colL) * 32 + rowQ * 8);
        #pragma unroll
        for (int j = 0; j < 4; ++j)
            bf[j] = *(const half8*)(lsB + (rn + j * 16 + colL) * 32 + rowQ * 8);
        #pragma unroll
        for (int i = 0; i < 4; ++i)
            #pragma unroll
            for (int j = 0; j < 4; ++j)
                acc[i][j] = __builtin_amdgcn_mfma_f32_16x16x32_f16(af[i], bf[j], acc[i][j], 0, 0, 0);
        __syncthreads();
    }

    #pragma unroll
    for (int j = 0; j < 4; ++j) {
        int gn = n0 + rn + j * 16 + colL;
        float bv = bias[gn];
        #pragma unroll
        for (int i = 0; i < 4; ++i) {
            #pragma unroll
            for (int r = 0; r < 4; ++r) {
                int gm = m0 + rm + i * 16 + rowQ * 4 + r;
                H[(size_t)gm * N2 + gn] = crelu_f(acc[i][j][r] + bv);
            }
        }
    }
}

// ---------------- K5: tail (h2 + h3, bucket-selected) ----------------
__global__ __launch_bounds__(256) void tail_kernel(
    const float* __restrict__ H,       // (B, 256), already crelu'd h1
    const int* __restrict__ bucket,
    const float* __restrict__ h2w,     // (8,32,32)
    const float* __restrict__ h2b,     // (8,32)
    const float* __restrict__ h3w,     // (8,1,32)
    const float* __restrict__ h3b,     // (8,1)
    float* __restrict__ out, int B)
{
    int s = blockIdx.x * 8 + (threadIdx.x >> 5);
    int j = threadIdx.x & 31;
    if (s >= B) return;
    int k = bucket[s];
    float h1v = H[(size_t)s * N2 + k * 32 + j];
    const float* w2 = h2w + ((k * 32 + j) * 32);
    float a = h2b[k * 32 + j];
    #pragma unroll
    for (int i = 0; i < 32; ++i) a += w2[i] * __shfl(h1v, i, 32);
    a = crelu_f(a);
    float p = a * h3w[k * 32 + j];
    #pragma unroll
    for (int off = 16; off; off >>= 1) p += __shfl_down(p, off, 32);
    if (j == 0) out[s] = p + h3b[k];
}

extern "C" void kernel_launch(void* const* d_in, const int* in_sizes, int n_in,
                              void* d_out, int out_size, void* d_ws, size_t ws_size,
                              hipStream_t stream) {
    const float* x    = (const float*)d_in[0];
    const float* ftw  = (const float*)d_in[1];
    const float* ftb  = (const float*)d_in[2];
    const float* h1w  = (const float*)d_in[3];
    const float* h1b  = (const float*)d_in[4];
    const float* h2w  = (const float*)d_in[5];
    const float* h2b  = (const float*)d_in[6];
    const float* h3w  = (const float*)d_in[7];
    const float* h3b  = (const float*)d_in[8];
    float* out = (float*)d_out;

    int B = in_sizes[0] / (2 * INF);          // 65536

    // workspace layout
    char* ws = (char*)d_ws;
    _Float16* x16   = (_Float16*)ws;                          // 2B*800*2 = 209,715,200
    size_t x16_b    = (size_t)2 * B * KP * sizeof(_Float16);
    _Float16* C1    = (_Float16*)(ws + x16_b);                // 2B*512*2 = 134,217,728
    size_t c1_b     = (size_t)2 * B * FT * sizeof(_Float16);
    _Float16* ftw16 = (_Float16*)(ws + x16_b + c1_b);         // 512*800*2
    _Float16* h1w16 = ftw16 + (size_t)FT * KP;                // 256*1024*2
    int* bucket     = (int*)(h1w16 + (size_t)N2 * K2);        // B*4
    float* H        = (float*)ws;                             // alias x16 (dead after GEMM1): B*256*4

    // K2: weights (independent of K1)
    {
        int total = FT * KP + N2 * K2;
        convert_w_kernel<<<(total + 255) / 256, 256, 0, stream>>>(ftw, h1w, ftw16, h1w16);
    }
    // K1: x conversion + bucket
    convert_x_kernel<<<B, 256, 0, stream>>>(x, x16, bucket, B);
    // K3: FT GEMM
    {
        int grid = (2 * B / 128) * 4;
        gemm_ft_kernel<<<grid, 256, 0, stream>>>(x16, ftw16, ftb, C1);
    }
    // K4: h1 GEMM (writes H over dead x16 region)
    {
        int grid = (B / 128) * 2;
        gemm_h1_kernel<<<grid, 256, 0, stream>>>(C1, h1w16, h1b, H, B);
    }
    // K5: tail
    tail_kernel<<<(B + 7) / 8, 256, 0, stream>>>(H, bucket, h2w, h2b, h3w, h3b, out, B);
}